// Round 5
// baseline (996.961 us; speedup 1.0000x reference)
//
#include <hip/hip_runtime.h>

// FSAS slab pipeline, 4 slabs of 64 rows, bf16 intermediates:
//   k2: affine(kv) + 1x1 conv 64->384 -> hid bf16 slab (66 rows incl. halo)
//   k3: grouped 3x3 -> qkv bf16 slab, PATCHIFIED [ch][patch(256)][64]
//   kC: per-patch: chunked LDS circular conv + LN + *v + proj 128->64 -> out
// Workspace:
//   kv  fp32 @ 0      (512)
//   whT fp32 @ 512    (24576)
//   wpT fp32 @ 25088  (8192)
//   hid bf16 @ float-ofs 40960 : [4][384][66][256]
//   qkv bf16 after hid          : [4][384][256][64]
// Total 97.66 MiB.

#define HW    65536
#define SLAB  64
#define HROWS 66
#define HSZ2  (HROWS*256)
#define QS    16384

__device__ __forceinline__ unsigned short f2bf(float f) {
    unsigned u = __float_as_uint(f);
    u += 0x7FFFu + ((u >> 16) & 1u);       // RNE
    return (unsigned short)(u >> 16);
}
__device__ __forceinline__ float bflo(unsigned u) { return __uint_as_float(u << 16); }
__device__ __forceinline__ float bfhi(unsigned u) { return __uint_as_float(u & 0xFFFF0000u); }

__global__ void k_prep(const float* __restrict__ prior, const float* __restrict__ wk,
                       const float* __restrict__ wh, const float* __restrict__ wp,
                       float* __restrict__ kv, float* __restrict__ whT, float* __restrict__ wpT) {
    int t = blockIdx.x * 256 + threadIdx.x;
    if (t < 512) {
        int b = t >> 7, k = t & 127;
        const float* p = prior + b * 192;
        const float* w = wk + k * 192;
        float s = 0.f;
        for (int f = 0; f < 192; ++f) s = fmaf(p[f], w[f], s);
        kv[t] = s;
        return;
    }
    t -= 512;
    if (t < 24576) {
        int c = t / 384, o = t - c * 384;
        whT[t] = wh[o * 64 + c];
        return;
    }
    t -= 24576;
    int c = t >> 6, o = t & 63;
    wpT[t] = wp[o * 128 + c];
}

__global__ __launch_bounds__(256, 2) void k2_hidden(const float* __restrict__ x,
    const float* __restrict__ whT, const float* __restrict__ kv,
    unsigned short* __restrict__ hid, int r0) {
    int row = blockIdx.x * 2 + (threadIdx.x >> 7);   // 0..65
    int cp = threadIdx.x & 127;
    int chunk = blockIdx.y;          // 0..5
    int b = blockIdx.z;
    int g = r0 - 1 + row;
    unsigned* hb = (unsigned*)(hid + ((size_t)(b * 384 + chunk * 64)) * HSZ2
                               + row * 256 + cp * 2);
    if (g < 0 || g > 255) {
        #pragma unroll
        for (int j = 0; j < 64; ++j) hb[(size_t)j * (HSZ2 / 2)] = 0u;
        return;
    }
    const float2* xb = (const float2*)(x + (size_t)b * 64 * HW + g * 256 + cp * 2);
    const float* kv1 = kv + b * 128;
    const float* kv2 = kv1 + 64;
    float acc0[64], acc1[64];
    #pragma unroll
    for (int j = 0; j < 64; ++j) { acc0[j] = 0.f; acc1[j] = 0.f; }
    #pragma unroll 4
    for (int c = 0; c < 64; ++c) {
        float2 xv = xb[(size_t)c * (HW / 2)];
        float xp0 = fmaf(xv.x, kv1[c], kv2[c]);
        float xp1 = fmaf(xv.y, kv1[c], kv2[c]);
        const float* wr = whT + c * 384 + chunk * 64;
        #pragma unroll
        for (int j = 0; j < 64; ++j) {
            acc0[j] = fmaf(wr[j], xp0, acc0[j]);
            acc1[j] = fmaf(wr[j], xp1, acc1[j]);
        }
    }
    #pragma unroll
    for (int j = 0; j < 64; ++j)
        hb[(size_t)j * (HSZ2 / 2)] = (unsigned)f2bf(acc0[j]) | ((unsigned)f2bf(acc1[j]) << 16);
}

__global__ __launch_bounds__(256) void k3_dw(const unsigned short* __restrict__ hid,
    const float* __restrict__ wdw, unsigned short* __restrict__ qkv) {
    __shared__ float sIn[2 * 18 * 66];
    int t = threadIdx.x;
    int bid = blockIdx.x;            // 16 tiles: tx 0..3, ty 0..3
    int gl = blockIdx.y;             // 0..191
    int b = blockIdx.z;
    int tx = bid & 3, ty = bid >> 2;
    int x0 = tx * 64, y0 = ty * 16;
    const unsigned short* hbase = hid + ((size_t)(b * 384 + 2 * gl)) * HSZ2;
    for (int idx = t; idx < 2 * 18 * 66; idx += 256) {
        int chl = idx >= 1188;
        int rem = idx - chl * 1188;
        int row = rem / 66;
        int col = rem - row * 66;
        int gx = x0 + col - 1;
        float v = 0.f;
        if (gx >= 0 && gx < 256)
            v = bflo((unsigned)hbase[(size_t)chl * HSZ2 + (y0 + row) * 256 + gx]);
        sIn[idx] = v;
    }
    __syncthreads();
    int og = 2 * gl;
    float w0[18], w1[18];
    #pragma unroll
    for (int i = 0; i < 18; ++i) {
        w0[i] = wdw[(size_t)og * 18 + i];
        w1[i] = wdw[(size_t)(og + 1) * 18 + i];
    }
    unsigned short* q0 = qkv + ((size_t)(b * 384 + og)) * QS;
    #pragma unroll
    for (int pp = 0; pp < 2; ++pp) {
        int ly = pp * 8 + (t >> 5);
        int lxp = (t & 31) * 2;
        float a[2][2];
        #pragma unroll
        for (int px = 0; px < 2; ++px) {
            float s0 = 0.f, s1 = 0.f;
            #pragma unroll
            for (int i = 0; i < 2; ++i)
                #pragma unroll
                for (int ky = 0; ky < 3; ++ky)
                    #pragma unroll
                    for (int kx = 0; kx < 3; ++kx) {
                        float v = sIn[i * 1188 + (ly + ky) * 66 + (lxp + px + kx)];
                        s0 = fmaf(w0[i * 9 + ky * 3 + kx], v, s0);
                        s1 = fmaf(w1[i * 9 + ky * 3 + kx], v, s1);
                    }
            a[px][0] = s0; a[px][1] = s1;
        }
        int row = y0 + ly;
        int gx = x0 + lxp;
        int patch = (row >> 3) * 32 + (gx >> 3);
        int off = patch * 64 + (row & 7) * 8 + (gx & 7);
        ((unsigned*)(q0 + off))[0] =
            (unsigned)f2bf(a[0][0]) | ((unsigned)f2bf(a[1][0]) << 16);
        ((unsigned*)(q0 + QS + off))[0] =
            (unsigned)f2bf(a[0][1]) | ((unsigned)f2bf(a[1][1]) << 16);
    }
}

// Fused per-patch: chunked-LDS circular conv + LN(128) + *v + proj 128->64.
// Channels processed in 4 chunks of 32; per-thread arrays <= 8 elems, all
// register indices compile-time -> no scratch.
__global__ __launch_bounds__(256) void kC_patch(const unsigned short* __restrict__ qkv,
    const float* __restrict__ wpT, const float* __restrict__ lnw,
    const float* __restrict__ lnb, float* __restrict__ outp, int r0) {
    __shared__ float sQ[32 * 65];                // [c_local][64], stride 65
    __shared__ float sK[32 * 65];
    __shared__ float sConv[64 * 129];            // [pix][c], stride 129
    __shared__ float sRedS[256], sRedQ[256];
    __shared__ float sMu[64], sRstd[64];
    int t = threadIdx.x;
    int p = blockIdx.x;              // slab-local patch 0..255
    int b = blockIdx.y;

    int cl = t >> 3;                 // 0..31 (staging + conv channel)
    int r  = t & 7;                  // staging row / conv py
    for (int ck = 0; ck < 4; ++ck) {
        // stage q,k chunk: one uint4 (8 bf16 = one patch row) each
        size_t ga = ((size_t)(b * 384 + ck * 32 + cl)) * QS + p * 64 + r * 8;
        uint4 uq = *(const uint4*)(qkv + ga);
        uint4 uk = *(const uint4*)(qkv + ga + (size_t)128 * QS);
        int sb = cl * 65 + r * 8;
        sQ[sb + 0] = bflo(uq.x); sQ[sb + 1] = bfhi(uq.x);
        sQ[sb + 2] = bflo(uq.y); sQ[sb + 3] = bfhi(uq.y);
        sQ[sb + 4] = bflo(uq.z); sQ[sb + 5] = bfhi(uq.z);
        sQ[sb + 6] = bflo(uq.w); sQ[sb + 7] = bfhi(uq.w);
        sK[sb + 0] = bflo(uk.x); sK[sb + 1] = bfhi(uk.x);
        sK[sb + 2] = bflo(uk.y); sK[sb + 3] = bfhi(uk.y);
        sK[sb + 4] = bflo(uk.z); sK[sb + 5] = bfhi(uk.z);
        sK[sb + 6] = bflo(uk.w); sK[sb + 7] = bfhi(uk.w);
        __syncthreads();
        // conv task: (cl, py=r) -> output row r of channel ck*32+cl
        float acc[8];
        #pragma unroll
        for (int px = 0; px < 8; ++px) acc[px] = 0.f;
        #pragma unroll
        for (int iy = 0; iy < 8; ++iy) {
            float qr[8], kr[8];
            #pragma unroll
            for (int ix = 0; ix < 8; ++ix) qr[ix] = sQ[cl * 65 + iy * 8 + ix];
            int krow = (r - iy) & 7;             // runtime LDS address (ok)
            #pragma unroll
            for (int ix = 0; ix < 8; ++ix) kr[ix] = sK[cl * 65 + krow * 8 + ix];
            #pragma unroll
            for (int ix = 0; ix < 8; ++ix)
                #pragma unroll
                for (int px = 0; px < 8; ++px)
                    acc[px] = fmaf(qr[ix], kr[(px - ix) & 7], acc[px]);
        }
        #pragma unroll
        for (int px = 0; px < 8; ++px)
            sConv[(r * 8 + px) * 129 + (ck * 32 + cl)] = acc[px];
        __syncthreads();
    }

    // prefetch v: thread (c = t&127, pyh = t>>7) covers 32 pixels (4 uint4)
    int c = t & 127;
    int pyh = t >> 7;
    const uint4* gv = (const uint4*)(qkv + ((size_t)(b * 384 + 256 + c)) * QS
                                     + p * 64 + pyh * 32);
    uint4 v0 = gv[0], v1 = gv[1], v2 = gv[2], v3 = gv[3];
    float lw = lnw[c], lb = lnb[c];

    // LN stats
    {
        int px = t & 63, q4 = t >> 6;
        float s = 0.f, s2 = 0.f;
        #pragma unroll
        for (int j = 0; j < 32; ++j) {
            float v = sConv[px * 129 + q4 * 32 + j];
            s += v;
            s2 = fmaf(v, v, s2);
        }
        sRedS[q4 * 64 + px] = s;
        sRedQ[q4 * 64 + px] = s2;
    }
    __syncthreads();
    if (t < 64) {
        float s  = sRedS[t] + sRedS[64 + t] + sRedS[128 + t] + sRedS[192 + t];
        float s2 = sRedQ[t] + sRedQ[64 + t] + sRedQ[128 + t] + sRedQ[192 + t];
        float mu = s * (1.f / 128.f);
        float var = s2 * (1.f / 128.f) - mu * mu;
        sMu[t] = mu;
        sRstd[t] = rsqrtf(var + 1e-5f);
    }
    __syncthreads();
    // tv = (norm(conv)*lnw+lnb)*v -> back into sConv (thread: channel c, 32 pix)
    {
        float vf[8];
        #pragma unroll
        for (int g4 = 0; g4 < 4; ++g4) {
            uint4 u = (g4 == 0) ? v0 : (g4 == 1) ? v1 : (g4 == 2) ? v2 : v3;
            vf[0] = bflo(u.x); vf[1] = bfhi(u.x);
            vf[2] = bflo(u.y); vf[3] = bfhi(u.y);
            vf[4] = bflo(u.z); vf[5] = bfhi(u.z);
            vf[6] = bflo(u.w); vf[7] = bfhi(u.w);
            #pragma unroll
            for (int j = 0; j < 8; ++j) {
                int pix = pyh * 32 + g4 * 8 + j;
                float cv = sConv[pix * 129 + c];
                float tvv = fmaf((cv - sMu[pix]) * sRstd[pix], lw, lb) * vf[j];
                sConv[pix * 129 + c] = tvv;
            }
        }
    }
    __syncthreads();
    // proj 128->64
    {
        int px = t & 63, og = (t >> 6) * 16;
        float po[16];
        #pragma unroll
        for (int j = 0; j < 16; ++j) po[j] = 0.f;
        #pragma unroll 2
        for (int cc = 0; cc < 128; ++cc) {
            float tvv = sConv[px * 129 + cc];
            const float* wr = wpT + cc * 64 + og;
            #pragma unroll
            for (int j = 0; j < 16; ++j) po[j] = fmaf(wr[j], tvv, po[j]);
        }
        int grow = r0 + (p >> 5) * 8 + (px >> 3);
        int gcol = (p & 31) * 8 + (px & 7);
        float* ob = outp + ((size_t)(b * 64 + og)) * HW + grow * 256 + gcol;
        #pragma unroll
        for (int j = 0; j < 16; ++j) ob[(size_t)j * HW] = po[j];
    }
}

extern "C" void kernel_launch(void* const* d_in, const int* in_sizes, int n_in,
                              void* d_out, int out_size, void* d_ws, size_t ws_size,
                              hipStream_t stream) {
    const float* x     = (const float*)d_in[0];
    const float* prior = (const float*)d_in[1];
    const float* wk    = (const float*)d_in[2];
    const float* wh    = (const float*)d_in[3];
    const float* wdw   = (const float*)d_in[4];
    const float* wp    = (const float*)d_in[5];
    const float* lnw   = (const float*)d_in[6];
    const float* lnb   = (const float*)d_in[7];
    float* out = (float*)d_out;
    float* ws  = (float*)d_ws;

    float* kv  = ws;
    float* whT = ws + 512;
    float* wpT = ws + 512 + 24576;
    unsigned short* hid = (unsigned short*)(ws + 40960);
    unsigned short* qkv = hid + (size_t)4 * 384 * HSZ2;

    k_prep<<<dim3(130), dim3(256), 0, stream>>>(prior, wk, wh, wp, kv, whT, wpT);
    for (int slab = 0; slab < 4; ++slab) {
        int r0 = slab * SLAB;
        k2_hidden<<<dim3(HROWS / 2, 6, 4), dim3(256), 0, stream>>>(x, whT, kv, hid, r0);
        k3_dw<<<dim3(16, 192, 4), dim3(256), 0, stream>>>(hid, wdw, qkv);
        kC_patch<<<dim3(256, 4), dim3(256), 0, stream>>>(qkv, wpT, lnw, lnb, out, r0);
    }
}